// Round 17
// baseline (203.532 us; speedup 1.0000x reference)
//
#include <hip/hip_runtime.h>
#include <hip/hip_bf16.h>

#define HID 128
#define IN_DIM 16

typedef short bf16x8 __attribute__((ext_vector_type(8)));
typedef float f32x4 __attribute__((ext_vector_type(4)));
typedef float f32x2 __attribute__((ext_vector_type(2)));
typedef unsigned short u16x8 __attribute__((ext_vector_type(8)));
typedef unsigned int u32x4 __attribute__((ext_vector_type(4)));

// ---------- bf16 helpers (RNE) ----------
__device__ __forceinline__ unsigned short f2bf(float f) {
    unsigned int u = __float_as_uint(f);
    unsigned int r = (u + 0x7FFFu + ((u >> 16) & 1u)) >> 16;
    return (unsigned short)r;
}
__device__ __forceinline__ float bf2f(unsigned short u) {
    return __uint_as_float(((unsigned int)u) << 16);
}

// ---------------- B1: per-block bucket histogram (LDS atomics only) ----------------
__global__ __launch_bounds__(256) void k_hist(const int* __restrict__ dst,
                                              int* __restrict__ hist,
                                              int E, int NB, int chunk) {
    __shared__ int lh[256];
    lh[threadIdx.x] = 0;
    __syncthreads();
    int s0 = blockIdx.x * chunk;
    int e_end = min(E, s0 + chunk);
    for (int e = s0 + threadIdx.x; e < e_end; e += 256)
        atomicAdd(&lh[dst[e] >> 8], 1);
    __syncthreads();
    for (int i = threadIdx.x; i < NB; i += 256)
        hist[blockIdx.x * NB + i] = lh[i];   // [blk][b]
}

// ---------------- B2a: column exclusive scan of hist over blk + per-bucket totals ----------------
__global__ __launch_bounds__(256) void k_hist_scan(int* __restrict__ hist,
                                                   int* __restrict__ btot, int NB) {
    __shared__ int sdata[256];
    int b = blockIdx.x, t = threadIdx.x;
    int v = hist[t * NB + b];
    sdata[t] = v;
    __syncthreads();
    for (int off = 1; off < 256; off <<= 1) {
        int tmp = (t >= off) ? sdata[t - off] : 0;
        __syncthreads();
        sdata[t] += tmp;
        __syncthreads();
    }
    hist[t * NB + b] = sdata[t] - v;     // exclusive within column
    if (t == 255) btot[b] = sdata[255];
}

// ---------------- misc: bucket_base scan | per-graph counts | W2T | zero pooled ----------------
__global__ __launch_bounds__(256) void k_misc(const int* __restrict__ btot,
                                              int* __restrict__ bucket_base,
                                              const int* __restrict__ batch, float* __restrict__ cnt,
                                              const float* __restrict__ W2,
                                              unsigned short* __restrict__ W2T,
                                              float* __restrict__ pooled,
                                              int N, int G, int NB, int E) {
    int bid = blockIdx.x;
    int t = threadIdx.x;
    if (bid == 0) {
        __shared__ int sdata[256];
        int v = (t < NB) ? btot[t] : 0;
        sdata[t] = v;
        __syncthreads();
        for (int off = 1; off < 256; off <<= 1) {
            int tmp = (t >= off) ? sdata[t - off] : 0;
            __syncthreads();
            sdata[t] += tmp;
            __syncthreads();
        }
        if (t < NB) bucket_base[t] = sdata[t] - v;
        if (t == 0) bucket_base[NB] = E;
    } else if (bid == 1) {
        int g = t;
        if (g >= G) return;
        int lo = 0, hi = N;
        while (lo < hi) { int mid = (lo + hi) >> 1; if (batch[mid] < g) lo = mid + 1; else hi = mid; }
        int start = lo;
        lo = 0; hi = N;
        while (lo < hi) { int mid = (lo + hi) >> 1; if (batch[mid] <= g) lo = mid + 1; else hi = mid; }
        cnt[g] = (float)(lo - start);
    } else if (bid < 66) {
        int i = (bid - 2) * 256 + t;     // 0..16383
        int n = i >> 7, k = i & 127;
        W2T[i] = f2bf(W2[(size_t)k * HID + n]);
    } else {
        int i = (bid - 66) * 256 + t;
        if (i < G * HID) pooled[i] = 0.f;
    }
}

// ---------------- B3: scatter packed edges into bucket-grouped array ----------------
__global__ __launch_bounds__(256) void k_bucket(const int* __restrict__ src, const int* __restrict__ dst,
                                                const int* __restrict__ hist,
                                                const int* __restrict__ bucket_base,
                                                unsigned int* __restrict__ bucketed,
                                                int E, int NB, int chunk) {
    __shared__ int lcur[256];
    for (int i = threadIdx.x; i < NB; i += 256)
        lcur[i] = hist[blockIdx.x * NB + i] + bucket_base[i];
    __syncthreads();
    int s0 = blockIdx.x * chunk;
    int e_end = min(E, s0 + chunk);
    for (int e = s0 + threadIdx.x; e < e_end; e += 256) {
        int d = dst[e], s = src[e];
        int p = atomicAdd(&lcur[d >> 8], 1);
        bucketed[p] = ((unsigned int)(d & 255) << 16) | (unsigned int)s;
    }
}

// ---------------- B4: per-bucket CSR fill + degree/offs/dinv (no global atomics) ----------------
__global__ __launch_bounds__(256) void k_fill3(const unsigned int* __restrict__ bucketed,
                                               const int* __restrict__ bucket_base,
                                               unsigned short* __restrict__ csr,
                                               int* __restrict__ offs,
                                               int* __restrict__ indeg,
                                               float* __restrict__ dinv, int N) {
    __shared__ int lh[256];
    __shared__ int sc[256];
    int b = blockIdx.x, t = threadIdx.x;
    int n0 = b << 8;
    lh[t] = 0;
    __syncthreads();
    int bb = bucket_base[b], be = bucket_base[b + 1];
    for (int e = bb + t; e < be; e += 256)
        atomicAdd(&lh[bucketed[e] >> 16], 1);
    __syncthreads();
    int deg = lh[t];
    sc[t] = deg;
    __syncthreads();
    for (int off = 1; off < 256; off <<= 1) {
        int tmp = (t >= off) ? sc[t - off] : 0;
        __syncthreads();
        sc[t] += tmp;
        __syncthreads();
    }
    int excl = sc[t] - deg + bb;
    int node = n0 + t;
    if (node < N) {
        offs[node] = excl;
        indeg[node] = deg;
        dinv[node] = rsqrtf(1.0f + (float)deg);
    }
    __syncthreads();
    sc[t] = excl;                         // cursor
    __syncthreads();
    for (int e = bb + t; e < be; e += 256) {
        unsigned int u = bucketed[e];
        int p = atomicAdd(&sc[u >> 16], 1);
        csr[p] = (unsigned short)(u & 0xFFFFu);
    }
}

// ---------------- prep: xs16[i] = bf16(dinv_i * x_i) ----------------
__global__ __launch_bounds__(256) void k_prep(const float* __restrict__ x,
                                              const float* __restrict__ dinv,
                                              unsigned short* __restrict__ xs16, int N) {
    int tt = blockIdx.x * 256 + threadIdx.x;
    if (tt >= N * 4) return;
    int node = tt >> 2, q = tt & 3;
    float di = dinv[node];
    float4 v = *reinterpret_cast<const float4*>(x + (size_t)node * IN_DIM + q * 4);
    ushort4 o;
    o.x = f2bf(di * v.x); o.y = f2bf(di * v.y);
    o.z = f2bf(di * v.z); o.w = f2bf(di * v.w);
    *reinterpret_cast<ushort4*>(xs16 + (size_t)node * IN_DIM + q * 4) = o;
}

// ---------------- gather16: y[i] = xs16[i] + sum_j xs16[j]   (2 thr/node, ushort8, unroll 8) ----------------
__global__ __launch_bounds__(256) void k_gather16(const unsigned short* __restrict__ xs16,
                                                  const int* __restrict__ offs,
                                                  const int* __restrict__ indeg,
                                                  const unsigned short* __restrict__ csr,
                                                  float* __restrict__ y, int N) {
    int t = blockIdx.x * 256 + threadIdx.x;
    int node = t >> 1;
    if (node >= N) return;
    int c = (t & 1) * 8;
    int base = offs[node], deg = indeg[node];
    u16x8 ow = *reinterpret_cast<const u16x8*>(xs16 + (size_t)node * IN_DIM + c);
    float a[8];
    #pragma unroll
    for (int d = 0; d < 8; ++d) a[d] = bf2f(ow[d]);
    int j = 0;
    for (; j + 8 <= deg; j += 8) {
        int sI[8];
        #pragma unroll
        for (int u = 0; u < 8; ++u) sI[u] = csr[base + j + u];
        u16x8 v[8];
        #pragma unroll
        for (int u = 0; u < 8; ++u)
            v[u] = *reinterpret_cast<const u16x8*>(xs16 + (size_t)sI[u] * IN_DIM + c);
        #pragma unroll
        for (int u = 0; u < 8; ++u)
            #pragma unroll
            for (int d = 0; d < 8; ++d) a[d] += bf2f(v[u][d]);
    }
    for (; j < deg; ++j) {
        int s = csr[base + j];
        u16x8 v = *reinterpret_cast<const u16x8*>(xs16 + (size_t)s * IN_DIM + c);
        #pragma unroll
        for (int d = 0; d < 8; ++d) a[d] += bf2f(v[d]);
    }
    float* yp = y + (size_t)node * IN_DIM + c;
    *reinterpret_cast<float4*>(yp + 0) = make_float4(a[0], a[1], a[2], a[3]);
    *reinterpret_cast<float4*>(yp + 4) = make_float4(a[4], a[5], a[6], a[7]);
}

// ---------------- GEMM1b: h1p8[i] = fp8_e4m3(dinv_i * relu(dinv_i*(y[i]@W1) + b1)) ----------------
// 4 cols/thread so fp8 packs into one u32 store.
__global__ __launch_bounds__(256) void k_gemm1b(const float* __restrict__ y,
                                                const float* __restrict__ W1,
                                                const float* __restrict__ dinv,
                                                const float* __restrict__ b1,
                                                unsigned int* __restrict__ out8, int N) {
    __shared__ float Ws[IN_DIM * HID];   // 8 KB
    __shared__ float xs[8][IN_DIM];      // 512 B
    int nb = blockIdx.x * 8;
    for (int i = threadIdx.x * 4; i < IN_DIM * HID; i += 256 * 4)
        *reinterpret_cast<float4*>(&Ws[i]) = *reinterpret_cast<const float4*>(&W1[i]);
    int nrows = min(8, N - nb);
    if (threadIdx.x < 32) {
        int r = threadIdx.x >> 2, c = (threadIdx.x & 3) * 4;
        if (r < nrows)
            *reinterpret_cast<float4*>(&xs[r][c]) =
                *reinterpret_cast<const float4*>(&y[(size_t)(nb + r) * IN_DIM + c]);
    }
    __syncthreads();
    int r = threadIdx.x >> 5;            // 0..7
    int c4 = (threadIdx.x & 31) * 4;     // 0..124
    if (r < nrows) {
        int node = nb + r;
        float a0 = 0.f, a1 = 0.f, a2 = 0.f, a3 = 0.f;
        #pragma unroll
        for (int k = 0; k < IN_DIM; ++k) {
            float xv = xs[r][k];
            const float* w = &Ws[k * HID + c4];
            a0 += xv * w[0]; a1 += xv * w[1]; a2 += xv * w[2]; a3 += xv * w[3];
        }
        float di = dinv[node];
        float v0 = di * fmaxf(di * a0 + b1[c4 + 0], 0.f);
        float v1 = di * fmaxf(di * a1 + b1[c4 + 1], 0.f);
        float v2 = di * fmaxf(di * a2 + b1[c4 + 2], 0.f);
        float v3 = di * fmaxf(di * a3 + b1[c4 + 3], 0.f);
        int p = __builtin_amdgcn_cvt_pk_fp8_f32(v0, v1, 0, false);   // bytes 0,1
        p = __builtin_amdgcn_cvt_pk_fp8_f32(v2, v3, p, true);        // bytes 2,3
        out8[(size_t)node * 32 + (c4 >> 2)] = (unsigned int)p;
    }
}

// ---------------- gather_z8: z[i] = fp8-decode(h1p8[i] + sum_j h1p8[j]) -> bf16 ----------------
// 8 thr/node, 16B (16 fp8) per thread per row, unroll 8.  HW cvt_pk_f32_fp8 decode.
__global__ __launch_bounds__(256) void k_gather_z8(const unsigned int* __restrict__ h1p8,
                                                   const int* __restrict__ offs,
                                                   const int* __restrict__ indeg,
                                                   const unsigned short* __restrict__ csr,
                                                   unsigned short* __restrict__ z, int N) {
    int t = blockIdx.x * 256 + threadIdx.x;
    int node = t >> 3;
    if (node >= N) return;
    int c = (t & 7) * 16;                 // fp8-element offset (16 per thread)
    int cw = c >> 2;                      // uint offset within row (32 uints/row)
    float a[16];
    {
        u32x4 ow = *reinterpret_cast<const u32x4*>(h1p8 + (size_t)node * 32 + cw);
        #pragma unroll
        for (int q = 0; q < 4; ++q) {
            f32x2 lo = __builtin_amdgcn_cvt_pk_f32_fp8(ow[q], false);
            f32x2 hi = __builtin_amdgcn_cvt_pk_f32_fp8(ow[q], true);
            a[q * 4 + 0] = lo[0]; a[q * 4 + 1] = lo[1];
            a[q * 4 + 2] = hi[0]; a[q * 4 + 3] = hi[1];
        }
    }
    int base = offs[node], deg = indeg[node];
    int j = 0;
    for (; j + 8 <= deg; j += 8) {
        int sI[8];
        #pragma unroll
        for (int u = 0; u < 8; ++u) sI[u] = csr[base + j + u];
        u32x4 v[8];
        #pragma unroll
        for (int u = 0; u < 8; ++u)
            v[u] = *reinterpret_cast<const u32x4*>(h1p8 + (size_t)sI[u] * 32 + cw);
        #pragma unroll
        for (int u = 0; u < 8; ++u) {
            #pragma unroll
            for (int q = 0; q < 4; ++q) {
                f32x2 lo = __builtin_amdgcn_cvt_pk_f32_fp8(v[u][q], false);
                f32x2 hi = __builtin_amdgcn_cvt_pk_f32_fp8(v[u][q], true);
                a[q * 4 + 0] += lo[0]; a[q * 4 + 1] += lo[1];
                a[q * 4 + 2] += hi[0]; a[q * 4 + 3] += hi[1];
            }
        }
    }
    for (; j < deg; ++j) {
        int s = csr[base + j];
        u32x4 v = *reinterpret_cast<const u32x4*>(h1p8 + (size_t)s * 32 + cw);
        #pragma unroll
        for (int q = 0; q < 4; ++q) {
            f32x2 lo = __builtin_amdgcn_cvt_pk_f32_fp8(v[q], false);
            f32x2 hi = __builtin_amdgcn_cvt_pk_f32_fp8(v[q], true);
            a[q * 4 + 0] += lo[0]; a[q * 4 + 1] += lo[1];
            a[q * 4 + 2] += hi[0]; a[q * 4 + 3] += hi[1];
        }
    }
    u16x8 o0, o1;
    #pragma unroll
    for (int d = 0; d < 8; ++d) { o0[d] = f2bf(a[d]); o1[d] = f2bf(a[8 + d]); }
    *reinterpret_cast<u16x8*>(z + (size_t)node * HID + c)     = o0;
    *reinterpret_cast<u16x8*>(z + (size_t)node * HID + c + 8) = o1;
}

// ---------------- GEMM2-MFMA + fused mean-pool (unfused, R11-proven) ----------------
// mfma_f32_16x16x32_bf16: A row=lane&15,k=(lane>>4)*8+j; D col=lane&15,row=(lane>>4)*4+reg [m89]
__global__ __launch_bounds__(256) void k_gemm2_pool(const unsigned short* __restrict__ z,
                                                    const unsigned short* __restrict__ W2T,
                                                    const float* __restrict__ dinv,
                                                    const float* __restrict__ b2,
                                                    const int* __restrict__ batch,
                                                    float* __restrict__ pooled, int N) {
    __shared__ float pool_s[HID];
    int wave = threadIdx.x >> 6;
    int lane = threadIdx.x & 63;
    int R = blockIdx.x * 64 + wave * 16;
    int lr = lane & 15;
    int lk = (lane >> 4) * 8;
    f32x4 acc[8] = {};
    const unsigned short* arow = z + (size_t)(R + lr) * HID;
    #pragma unroll
    for (int kk = 0; kk < 4; ++kk) {
        bf16x8 a = *reinterpret_cast<const bf16x8*>(arow + kk * 32 + lk);
        #pragma unroll
        for (int cf = 0; cf < 8; ++cf) {
            bf16x8 b = *reinterpret_cast<const bf16x8*>(W2T + (size_t)(cf * 16 + lr) * HID + kk * 32 + lk);
            acc[cf] = __builtin_amdgcn_mfma_f32_16x16x32_bf16(a, b, acc[cf], 0, 0, 0);
        }
    }
    int r0 = (lane >> 4) * 4;
    float di[4];
    int nd[4];
    #pragma unroll
    for (int r = 0; r < 4; ++r) {
        nd[r] = R + r0 + r;
        di[r] = (nd[r] < N) ? dinv[nd[r]] : 0.f;
    }
    int R0 = blockIdx.x * 64;
    int gid0 = batch[min(R0, N - 1)];
    bool single = (R0 + 63 < N) && (batch[R0 + 63] == gid0);
    if (single) {
        if (threadIdx.x < HID) pool_s[threadIdx.x] = 0.f;
        __syncthreads();
        #pragma unroll
        for (int cf = 0; cf < 8; ++cf) {
            float bb = b2[cf * 16 + lr];
            float sc = 0.f;
            #pragma unroll
            for (int r = 0; r < 4; ++r)
                sc += fmaxf(di[r] * acc[cf][r] + bb, 0.f);
            sc += __shfl_xor(sc, 16);
            sc += __shfl_xor(sc, 32);
            if (lane < 16) atomicAdd(&pool_s[cf * 16 + lr], sc);
        }
        __syncthreads();
        if (threadIdx.x < HID)
            atomicAdd(&pooled[(size_t)gid0 * HID + threadIdx.x], pool_s[threadIdx.x]);
    } else {
        #pragma unroll
        for (int r = 0; r < 4; ++r) {
            if (nd[r] < N) {
                int bi = batch[nd[r]];
                #pragma unroll
                for (int cf = 0; cf < 8; ++cf) {
                    float v = fmaxf(di[r] * acc[cf][r] + b2[cf * 16 + lr], 0.f);
                    atomicAdd(&pooled[(size_t)bi * HID + cf * 16 + lr], v);
                }
            }
        }
    }
}

// ---------------- final FC ----------------
__global__ __launch_bounds__(256) void k_fc(const float* __restrict__ pooled,
                                            const float* __restrict__ cnt,
                                            const float* __restrict__ Wfc,
                                            const float* __restrict__ bfc,
                                            float* __restrict__ out, int G, int O) {
    int t = blockIdx.x * blockDim.x + threadIdx.x;
    if (t >= G * O) return;
    int g = t / O, o = t % O;
    float acc = 0.f;
    for (int k = 0; k < HID; ++k) acc += pooled[(size_t)g * HID + k] * Wfc[(size_t)k * O + o];
    out[t] = acc / fmaxf(cnt[g], 1.f) + bfc[o];
}

extern "C" void kernel_launch(void* const* d_in, const int* in_sizes, int n_in,
                              void* d_out, int out_size, void* d_ws, size_t ws_size,
                              hipStream_t stream) {
    const float* x     = (const float*)d_in[0];
    const int*   ei    = (const int*)d_in[1];
    const int*   batch = (const int*)d_in[2];
    const float* W1    = (const float*)d_in[3];
    const float* b1    = (const float*)d_in[4];
    const float* W2    = (const float*)d_in[5];
    const float* b2    = (const float*)d_in[6];
    const float* Wfc   = (const float*)d_in[7];
    const float* bfc   = (const float*)d_in[8];
    float* out = (float*)d_out;

    const int E = in_sizes[1] / 2;
    const int N = in_sizes[2];
    const int O = in_sizes[8];              // 16
    const int G = out_size / O;             // 64
    const int Npad = ((N + 63) / 64) * 64;
    const int NB = (N + 255) >> 8;          // 256-node buckets (<=256)
    const int CHUNK = (E + 255) / 256;

    const int* src = ei;
    const int* dst = ei + E;

    // workspace layout (all segment starts 16B-aligned for these sizes)
    char* ws = (char*)d_ws;
    int*   indeg  = (int*)ws;                        ws += sizeof(int) * N;
    float* pooled = (float*)ws;                      ws += sizeof(float) * G * HID;
    float* dinv   = (float*)ws;                      ws += sizeof(float) * N;
    int*   offs   = (int*)ws;                        ws += sizeof(int) * N;
    int*   hist   = (int*)ws;                        ws += sizeof(int) * 256 * NB;
    int*   btot   = (int*)ws;                        ws += sizeof(int) * 256;
    int*   bucket_base = (int*)ws;                   ws += sizeof(int) * 260;
    float* cnt    = (float*)ws;                      ws += sizeof(float) * G;
    float* y      = (float*)ws;                      ws += sizeof(float) * (size_t)N * IN_DIM;
    unsigned short* xs16 = (unsigned short*)ws;      ws += sizeof(unsigned short) * (size_t)N * IN_DIM;
    unsigned short* w2t  = (unsigned short*)ws;      ws += sizeof(unsigned short) * (size_t)HID * HID;
    unsigned int*  h1p8  = (unsigned int*)ws;        ws += sizeof(unsigned int) * (size_t)N * 32;   // fp8 rows
    unsigned short* z    = (unsigned short*)ws;      ws += sizeof(unsigned short) * (size_t)Npad * HID;
    unsigned int*  bucketed = (unsigned int*)ws;     ws += sizeof(unsigned int) * (size_t)E;
    unsigned short* csr  = (unsigned short*)ws;      ws += sizeof(unsigned short) * (size_t)E;

    const int BS = 256;

    k_hist<<<256, BS, 0, stream>>>(dst, hist, E, NB, CHUNK);
    k_hist_scan<<<NB, BS, 0, stream>>>(hist, btot, NB);
    k_misc<<<66 + (G * HID + BS - 1) / BS, BS, 0, stream>>>(btot, bucket_base, batch, cnt,
                                                            W2, w2t, pooled, N, G, NB, E);
    k_bucket<<<256, BS, 0, stream>>>(src, dst, hist, bucket_base, bucketed, E, NB, CHUNK);
    k_fill3<<<NB, BS, 0, stream>>>(bucketed, bucket_base, csr, offs, indeg, dinv, N);
    k_prep<<<(N * 4 + BS - 1) / BS, BS, 0, stream>>>(x, dinv, xs16, N);

    // conv1
    k_gather16<<<(N * 2 + BS - 1) / BS, BS, 0, stream>>>(xs16, offs, indeg, csr, y, N);
    k_gemm1b<<<(N + 7) / 8, BS, 0, stream>>>(y, W1, dinv, b1, h1p8, N);

    // conv2 (unfused: fp8 gather -> bf16 z; MFMA GEMM + pool)
    k_gather_z8<<<(N * 8 + BS - 1) / BS, BS, 0, stream>>>(h1p8, offs, indeg, csr, z, N);
    k_gemm2_pool<<<Npad / 64, BS, 0, stream>>>(z, w2t, dinv, b2, batch, pooled, N);

    // FC head
    k_fc<<<(G * O + BS - 1) / BS, BS, 0, stream>>>(pooled, cnt, Wfc, bfc, out, G, O);
}